// Round 2
// baseline (213.380 us; speedup 1.0000x reference)
//
#include <hip/hip_runtime.h>

typedef _Float16 f16x8 __attribute__((ext_vector_type(8)));
typedef _Float16 f16x2 __attribute__((ext_vector_type(2)));
typedef float    f32x4 __attribute__((ext_vector_type(4)));
typedef float    f32x16 __attribute__((ext_vector_type(16)));

#define N_CTX 16384
#define N_Q   4096
#define DIM   100
#define THR   4.0f

union PkU  { f16x2 h2; unsigned int u; };
union FragU { unsigned int u[4]; f16x8 v; };

static __device__ __forceinline__ unsigned short f2h_bits(float f) {
    union { _Float16 h; unsigned short u; } v;
    v.h = (_Float16)f;
    return v.u;
}

// ---------------- fused prep: qb + t (blocks 0..15), a (16..79), qT (80..191) ----
__global__ void prep_all(const float* __restrict__ q, const float* __restrict__ ctx,
                         const float* __restrict__ ker,
                         unsigned short* __restrict__ qb, unsigned short* __restrict__ qT,
                         float* __restrict__ t, float* __restrict__ a) {
    int b = blockIdx.x;
    int tid = threadIdx.x;
    if (b < 16) {
        int j = b * 256 + tid;
        const float* row = q + (size_t)j * DIM;
        unsigned short* orow = qb + (size_t)j * 128;
        float acc = 0.f;
        for (int d = 0; d < DIM; ++d) { float v = row[d]; acc += v * ker[100 + d]; orow[d] = f2h_bits(v); }
        for (int d = DIM; d < 128; ++d) orow[d] = 0;
        t[j] = acc;
    } else if (b < 80) {
        int i = (b - 16) * 256 + tid;
        const float* row = ctx + (size_t)i * DIM;
        float acc = 0.f;
        for (int d = 0; d < DIM; ++d) acc += row[d] * ker[d];
        a[i] = acc;
    } else {
        int d = b - 80;                 // 0..111
        for (int j = tid; j < N_Q; j += 256)
            qT[(size_t)d * N_Q + j] = (d < DIM) ? f2h_bits(q[(size_t)j * DIM + d])
                                                : (unsigned short)0;
    }
}

// ---------------- main fused attention ----------------
// 512 blocks x 512 thr (8 waves). Block owns rows [i0,i0+32); wave w sweeps
// j in [w*512,(w+1)*512) by 32, online softmax with defer-max. 32x32x16 MFMA.
__global__ __launch_bounds__(512, 4) void attn_main(
    const unsigned short* __restrict__ qb, const unsigned short* __restrict__ qT,
    const float* __restrict__ t, const float* __restrict__ a,
    const float* __restrict__ ctx, const float* __restrict__ ker,
    float* __restrict__ G, float* __restrict__ mfull)
{
    __shared__ _Float16 cbL[32 * 128];          // (c*w3) tile, XOR-swizzled rows
    __shared__ _Float16 smU[8][100][32];        // per-wave U^T partials (fp16)
    __shared__ float smM[8][32], smL[8][32], smMt[8][32];

    const int tid  = threadIdx.x;
    const int w    = tid >> 6;
    const int lane = tid & 63;
    const int hi   = lane >> 5;
    const int c31  = lane & 31;
    const int i0   = blockIdx.x * 32;

    // stage cb: row i = ctx row, col d: fp16(ctx[i][d] * w3[d]); swizzle byte^=((i&7)<<4)
    {
        int i  = tid >> 4;              // 0..31
        int d0 = (tid & 15) * 8;        // 0..120
        const float* crow = ctx + (size_t)(i0 + i) * DIM;
        f16x8 v;
        #pragma unroll
        for (int e = 0; e < 8; ++e) {
            int d = d0 + e;
            v[e] = (d < DIM) ? (_Float16)(crow[d] * ker[200 + d]) : (_Float16)0.f;
        }
        int byte = (i * 256 + d0 * 2) ^ ((i & 7) << 4);
        *reinterpret_cast<f16x8*>(reinterpret_cast<char*>(cbL) + byte) = v;
    }
    __syncthreads();

    f32x16 U0 = {}, U1 = {}, U2 = {}, U3 = {};   // U^T d-tiles 0..3 (d = 32*dt + row)
    float m = -INFINITY, mtrue = -INFINITY, l = 0.f;

    const int cbase = c31 * 256;
    const int cswz  = (c31 & 7) << 4;

    int j0 = w * 512;
    #pragma unroll 2
    for (int s = 0; s < 16; ++s, j0 += 32) {
        // ---- QK^T: S^T[j(0..31)][i(0..31)] ----
        f32x16 sc = {};
        const unsigned short* qrow = qb + (size_t)(j0 + c31) * 128 + 8 * hi;
        #pragma unroll
        for (int kk = 0; kk < 7; ++kk) {
            f16x8 aq = *reinterpret_cast<const f16x8*>(qrow + kk * 16);
            int cb = (cbase + kk * 32 + 16 * hi) ^ cswz;
            f16x8 bq = *reinterpret_cast<const f16x8*>(reinterpret_cast<const char*>(cbL) + cb);
            sc = __builtin_amdgcn_mfma_f32_32x32x16_f16(aq, bq, sc, 0, 0, 0);
        }

        // ---- bias + tile max (row j = (r&3)+8*(r>>2)+4*hi) ----
        const float* tb = t + j0 + 4 * hi;
        #pragma unroll
        for (int qd = 0; qd < 4; ++qd) {
            f32x4 tv = *reinterpret_cast<const f32x4*>(tb + 8 * qd);
            sc[4*qd+0] += tv[0]; sc[4*qd+1] += tv[1];
            sc[4*qd+2] += tv[2]; sc[4*qd+3] += tv[3];
        }
        float tm = sc[0];
        #pragma unroll
        for (int r = 1; r < 16; ++r) tm = fmaxf(tm, sc[r]);
        tm = fmaxf(tm, __shfl_xor(tm, 32, 64));
        mtrue = fmaxf(mtrue, tm);

        if (__any(tm > m + THR)) {                 // defer-max: rescale rarely
            float mn = fmaxf(m, tm);
            float scale = __expf(m - mn);
            U0 *= scale; U1 *= scale; U2 *= scale; U3 *= scale;
            l *= scale;
            m = mn;
        }

        float ps = 0.f;
        #pragma unroll
        for (int r = 0; r < 16; ++r) { sc[r] = __expf(sc[r] - m); ps += sc[r]; }
        l += ps;

        // ---- P -> PV B-operand (pack pairs, exchange halves via shfl_xor 32) ----
        unsigned int pk[8], pr[8];
        #pragma unroll
        for (int h2 = 0; h2 < 8; ++h2) {
            PkU u; u.h2[0] = (_Float16)sc[2*h2]; u.h2[1] = (_Float16)sc[2*h2+1];
            pk[h2] = u.u;
            pr[h2] = (unsigned int)__shfl_xor((int)pk[h2], 32, 64);
        }
        FragU f0, f1;
        f0.u[0] = hi ? pr[2] : pk[0];
        f0.u[1] = hi ? pr[3] : pk[1];
        f0.u[2] = hi ? pk[2] : pr[0];
        f0.u[3] = hi ? pk[3] : pr[1];
        f1.u[0] = hi ? pr[6] : pk[4];
        f1.u[1] = hi ? pr[7] : pk[5];
        f1.u[2] = hi ? pk[6] : pr[4];
        f1.u[3] = hi ? pk[7] : pr[5];

        // ---- PV: U^T[d][i] += V^T[d][j] P^T[j][i] ----
        const unsigned short* vrow = qT + (size_t)c31 * N_Q + j0 + 8 * hi;
        f16x8 av;
        av = *reinterpret_cast<const f16x8*>(vrow);
        U0 = __builtin_amdgcn_mfma_f32_32x32x16_f16(av, f0.v, U0, 0, 0, 0);
        av = *reinterpret_cast<const f16x8*>(vrow + 16);
        U0 = __builtin_amdgcn_mfma_f32_32x32x16_f16(av, f1.v, U0, 0, 0, 0);
        av = *reinterpret_cast<const f16x8*>(vrow + 32 * N_Q);
        U1 = __builtin_amdgcn_mfma_f32_32x32x16_f16(av, f0.v, U1, 0, 0, 0);
        av = *reinterpret_cast<const f16x8*>(vrow + 32 * N_Q + 16);
        U1 = __builtin_amdgcn_mfma_f32_32x32x16_f16(av, f1.v, U1, 0, 0, 0);
        av = *reinterpret_cast<const f16x8*>(vrow + 64 * N_Q);
        U2 = __builtin_amdgcn_mfma_f32_32x32x16_f16(av, f0.v, U2, 0, 0, 0);
        av = *reinterpret_cast<const f16x8*>(vrow + 64 * N_Q + 16);
        U2 = __builtin_amdgcn_mfma_f32_32x32x16_f16(av, f1.v, U2, 0, 0, 0);
        av = *reinterpret_cast<const f16x8*>(vrow + 96 * N_Q);
        U3 = __builtin_amdgcn_mfma_f32_32x32x16_f16(av, f0.v, U3, 0, 0, 0);
        av = *reinterpret_cast<const f16x8*>(vrow + 96 * N_Q + 16);
        U3 = __builtin_amdgcn_mfma_f32_32x32x16_f16(av, f1.v, U3, 0, 0, 0);
    }

    l += __shfl_xor(l, 32, 64);

    // ---- stash per-wave partials ----
    #pragma unroll
    for (int r = 0; r < 16; ++r) {
        int dl = (r & 3) + 8 * (r >> 2) + 4 * hi;
        smU[w][dl][c31]      = (_Float16)U0[r];
        smU[w][32 + dl][c31] = (_Float16)U1[r];
        smU[w][64 + dl][c31] = (_Float16)U2[r];
        if (96 + dl < DIM) smU[w][96 + dl][c31] = (_Float16)U3[r];
    }
    if (lane < 32) {
        smM[w][c31] = m; smL[w][c31] = l; smMt[w][c31] = mtrue;
    }
    __syncthreads();

    // ---- split-K combine + epilogue (G cols 0..299, mfull) ----
    {
        int i32 = tid & 31;
        int seg = tid >> 5;                  // 0..15
        float M = -INFINITY;
        #pragma unroll
        for (int ww = 0; ww < 8; ++ww) M = fmaxf(M, smM[ww][i32]);
        float ew[8];
        float L = 0.f, Mt = -INFINITY;
        #pragma unroll
        for (int ww = 0; ww < 8; ++ww) {
            ew[ww] = __expf(smM[ww][i32] - M);
            L += smL[ww][i32] * ew[ww];
            Mt = fmaxf(Mt, smMt[ww][i32]);
        }
        int row = i0 + i32;
        if (seg == 0) mfull[row] = a[row] + Mt;
        float invL = 1.f / L;
        for (int d = seg; d < DIM; d += 16) {
            float u = 0.f;
            #pragma unroll
            for (int ww = 0; ww < 8; ++ww) u += (float)smU[ww][d][i32] * ew[ww];
            float ua = u * invL;
            float cv = ctx[(size_t)row * DIM + d];
            size_t base = (size_t)row * 400;
            G[base + d]       = cv;
            G[base + 100 + d] = ua;
            G[base + 200 + d] = ua * cv;
        }
    }
}

// ---------------- b-softmax + h ----------------
__global__ void kernel_h(const float* __restrict__ mfull, const float* __restrict__ ctx,
                         float* __restrict__ hp) {
    __shared__ float sm[256];
    int t = threadIdx.x;
    float v = -INFINITY;
    for (int i = t; i < N_CTX; i += 256) v = fmaxf(v, mfull[i]);
    sm[t] = v; __syncthreads();
    for (int s = 128; s > 0; s >>= 1) { if (t < s) sm[t] = fmaxf(sm[t], sm[t + s]); __syncthreads(); }
    float M = sm[0];
    __syncthreads();
    float z = 0.f;
    for (int i = t; i < N_CTX; i += 256) z += __expf(mfull[i] - M);
    sm[t] = z; __syncthreads();
    for (int s = 128; s > 0; s >>= 1) { if (t < s) sm[t] += sm[t + s]; __syncthreads(); }
    float Z = sm[0];
    if (t < DIM) {
        int i0 = blockIdx.x * 64;
        float acc = 0.f;
        for (int r = 0; r < 64; ++r)
            acc += __expf(mfull[i0 + r] - M) * ctx[(size_t)(i0 + r) * DIM + t];
        hp[t * 256 + blockIdx.x] = acc / Z;
    }
}

__global__ void kernel_hred(const float* __restrict__ hp, float* __restrict__ h) {
    __shared__ float sm[4][128];
    int t = threadIdx.x;
    int d = t & 127, rep = t >> 7;
    float s = 0.f;
    if (d < DIM) for (int b = 0; b < 64; ++b) s += hp[d * 256 + rep * 64 + b];
    sm[rep][d] = s;
    __syncthreads();
    if (rep == 0 && d < DIM) h[d] = sm[0][d] + sm[1][d] + sm[2][d] + sm[3][d];
}

__global__ void kernel_g4(const float* __restrict__ ctx, const float* __restrict__ h,
                          float* __restrict__ G) {
    int idx = blockIdx.x * 256 + threadIdx.x;
    if (idx >= N_CTX * DIM) return;
    int i = idx / DIM;
    int d = idx - i * DIM;
    G[(size_t)i * 400 + 300 + d] = ctx[idx] * h[d];
}

// ---------------- launcher ----------------
extern "C" void kernel_launch(void* const* d_in, const int* in_sizes, int n_in,
                              void* d_out, int out_size, void* d_ws, size_t ws_size,
                              hipStream_t stream) {
    const float* ctx = (const float*)d_in[0];
    const float* q   = (const float*)d_in[1];
    const float* ker = (const float*)d_in[2];
    float* G = (float*)d_out;

    char* ws = (char*)d_ws;
    unsigned short* qb    = (unsigned short*)(ws);                 // 4096*128*2 = 1,048,576
    unsigned short* qT    = (unsigned short*)(ws + 1048576);       // 128*4096*2 = 1,048,576
    float*          t     = (float*)(ws + 2097152);                // 16,384
    float*          a     = (float*)(ws + 2113536);                // 65,536
    float*          mfull = (float*)(ws + 2179072);                // 65,536
    float*          hp    = (float*)(ws + 2244608);                // 102,400
    float*          h     = (float*)(ws + 2347008);                // 400

    prep_all<<<dim3(192), dim3(256), 0, stream>>>(q, ctx, ker, qb, qT, t, a);
    attn_main<<<dim3(512), dim3(512), 0, stream>>>(qb, qT, t, a, ctx, ker, G, mfull);
    kernel_h<<<dim3(256), dim3(256), 0, stream>>>(mfull, ctx, hp);
    kernel_hred<<<dim3(1), dim3(512), 0, stream>>>(hp, h);
    kernel_g4<<<dim3(6400), dim3(256), 0, stream>>>(ctx, h, G);
}

// Round 3
// 176.386 us; speedup vs baseline: 1.2097x; 1.2097x over previous
//
#include <hip/hip_runtime.h>

typedef _Float16 f16x8 __attribute__((ext_vector_type(8)));
typedef _Float16 f16x2 __attribute__((ext_vector_type(2)));
typedef float    f32x4 __attribute__((ext_vector_type(4)));
typedef float    f32x16 __attribute__((ext_vector_type(16)));

#define N_CTX 16384
#define N_Q   4096
#define DIM   100
#define THR   4.0f

union PkU   { f16x2 h2; unsigned int u; };
union FragU { unsigned int u[4]; f16x8 v; };

static __device__ __forceinline__ unsigned short f2h_bits(float f) {
    union { _Float16 h; unsigned short u; } v;
    v.h = (_Float16)f;
    return v.u;
}

// ---------------- fused prep ----------------
// blocks 0..15   : qb rows + t   (256 rows/block)
// blocks 16..79  : a             (256 rows/block)
// blocks 80..143 : qT transpose  (64 q-rows/block), rows 100..127 zeroed
__global__ void prep_all(const float* __restrict__ q, const float* __restrict__ ctx,
                         const float* __restrict__ ker,
                         unsigned short* __restrict__ qb, unsigned short* __restrict__ qT,
                         float* __restrict__ t, float* __restrict__ a) {
    int b = blockIdx.x;
    int tid = threadIdx.x;
    if (b < 16) {
        int j = b * 256 + tid;
        const float* row = q + (size_t)j * DIM;
        float buf[100];
        float acc = 0.f;
        #pragma unroll
        for (int d4 = 0; d4 < 25; ++d4) {
            f32x4 v = *reinterpret_cast<const f32x4*>(row + 4 * d4);
            #pragma unroll
            for (int e = 0; e < 4; ++e) {
                buf[4 * d4 + e] = v[e];
                acc += v[e] * ker[100 + 4 * d4 + e];
            }
        }
        t[j] = acc;
        unsigned short* orow = qb + (size_t)j * 128;
        #pragma unroll
        for (int c = 0; c < 16; ++c) {
            f16x8 h;
            #pragma unroll
            for (int e = 0; e < 8; ++e) {
                int d = 8 * c + e;
                h[e] = (d < DIM) ? (_Float16)buf[d] : (_Float16)0.f;
            }
            *reinterpret_cast<f16x8*>(orow + 8 * c) = h;
        }
    } else if (b < 80) {
        int i = (b - 16) * 256 + tid;
        const float* row = ctx + (size_t)i * DIM;
        float acc = 0.f;
        #pragma unroll
        for (int d4 = 0; d4 < 25; ++d4) {
            f32x4 v = *reinterpret_cast<const f32x4*>(row + 4 * d4);
            acc += v[0] * ker[4 * d4] + v[1] * ker[4 * d4 + 1]
                 + v[2] * ker[4 * d4 + 2] + v[3] * ker[4 * d4 + 3];
        }
        a[i] = acc;
    } else {
        __shared__ _Float16 ldsT[100][64];
        int j0 = (b - 80) * 64;
        int r = tid >> 2, c = tid & 3;
        const float* row = q + (size_t)(j0 + r) * DIM + c * 25;
        #pragma unroll
        for (int k = 0; k < 25; ++k) ldsT[c * 25 + k][r] = (_Float16)row[k];
        __syncthreads();
        for (int idx = tid; idx < 128 * 64; idx += 256) {
            int d = idx >> 6, jj = idx & 63;
            qT[(size_t)d * N_Q + j0 + jj] = (d < DIM) ? *(unsigned short*)&ldsT[d][jj]
                                                      : (unsigned short)0;
        }
    }
}

// ---------------- main fused attention ----------------
// 512 blocks x 256 thr (4 waves). Block rows [i0,i0+32); wave w sweeps
// j in [w*1024,(w+1)*1024) by 32. 32x32x16 MFMA, online softmax + defer-max.
__global__ __launch_bounds__(256, 2) void attn_main(
    const unsigned short* __restrict__ qb, const unsigned short* __restrict__ qT,
    const float* __restrict__ t, const float* __restrict__ a,
    const float* __restrict__ ctx, const float* __restrict__ ker,
    float* __restrict__ G, float* __restrict__ mfull)
{
    __shared__ _Float16 cbL[32 * 128];
    __shared__ _Float16 smU[4][100][32];
    __shared__ float smM[4][32], smL[4][32], smMt[4][32];

    const int tid  = threadIdx.x;
    const int w    = tid >> 6;
    const int lane = tid & 63;
    const int hi   = lane >> 5;
    const int c31  = lane & 31;
    const int i0   = blockIdx.x * 32;

    // stage cb tile (fp16(ctx*w3)), XOR-swizzled rows
    {
        int i  = tid >> 3;              // 0..31
        int d0 = (tid & 7) * 16;        // 0..112
        const float* crow = ctx + (size_t)(i0 + i) * DIM;
        f16x8 v0, v1;
        #pragma unroll
        for (int e = 0; e < 8; ++e) {
            int d = d0 + e;
            v0[e] = (d < DIM) ? (_Float16)(crow[d] * ker[200 + d]) : (_Float16)0.f;
        }
        #pragma unroll
        for (int e = 0; e < 8; ++e) {
            int d = d0 + 8 + e;
            v1[e] = (d < DIM) ? (_Float16)(crow[d] * ker[200 + d]) : (_Float16)0.f;
        }
        int base = i * 256 + d0 * 2;
        int swz  = (i & 7) << 4;
        *reinterpret_cast<f16x8*>(reinterpret_cast<char*>(cbL) + ((base) ^ swz))      = v0;
        *reinterpret_cast<f16x8*>(reinterpret_cast<char*>(cbL) + ((base + 16) ^ swz)) = v1;
    }
    __syncthreads();

    // hoist cb B-fragments into persistent registers (28 VGPRs)
    f16x8 cbF[7];
    {
        int cswz = (c31 & 7) << 4;
        #pragma unroll
        for (int kk = 0; kk < 7; ++kk)
            cbF[kk] = *reinterpret_cast<const f16x8*>(
                reinterpret_cast<const char*>(cbL) + ((c31 * 256 + kk * 32 + hi * 16) ^ cswz));
    }

    f32x16 U0 = {}, U1 = {}, U2 = {}, U3 = {};
    float m = -INFINITY, mtrue = -INFINITY, l = 0.f;

    int j0 = w * 1024;
    for (int s = 0; s < 32; ++s, j0 += 32) {
        // ---- issue ALL global loads for this step up front ----
        const unsigned short* qrow = qb + (size_t)(j0 + c31) * 128 + 8 * hi;
        const unsigned short* vrow = qT + (size_t)c31 * N_Q + j0 + 8 * hi;
        f16x8 aq0 = *reinterpret_cast<const f16x8*>(qrow);
        f16x8 aq1 = *reinterpret_cast<const f16x8*>(qrow + 16);
        f16x8 aq2 = *reinterpret_cast<const f16x8*>(qrow + 32);
        f16x8 aq3 = *reinterpret_cast<const f16x8*>(qrow + 48);
        f16x8 aq4 = *reinterpret_cast<const f16x8*>(qrow + 64);
        f16x8 aq5 = *reinterpret_cast<const f16x8*>(qrow + 80);
        f16x8 aq6 = *reinterpret_cast<const f16x8*>(qrow + 96);
        f16x8 av0 = *reinterpret_cast<const f16x8*>(vrow);
        f16x8 av1 = *reinterpret_cast<const f16x8*>(vrow + 16);
        f16x8 av2 = *reinterpret_cast<const f16x8*>(vrow + 32 * N_Q);
        f16x8 av3 = *reinterpret_cast<const f16x8*>(vrow + 32 * N_Q + 16);
        f16x8 av4 = *reinterpret_cast<const f16x8*>(vrow + 64 * N_Q);
        f16x8 av5 = *reinterpret_cast<const f16x8*>(vrow + 64 * N_Q + 16);
        f16x8 av6 = *reinterpret_cast<const f16x8*>(vrow + 96 * N_Q);
        f16x8 av7 = *reinterpret_cast<const f16x8*>(vrow + 96 * N_Q + 16);
        const float* tb = t + j0 + 4 * hi;
        f32x4 tv0 = *reinterpret_cast<const f32x4*>(tb);
        f32x4 tv1 = *reinterpret_cast<const f32x4*>(tb + 8);
        f32x4 tv2 = *reinterpret_cast<const f32x4*>(tb + 16);
        f32x4 tv3 = *reinterpret_cast<const f32x4*>(tb + 24);

        // ---- QK^T: two interleaved accumulator chains ----
        f32x16 sa = {}, sb = {};
        sa = __builtin_amdgcn_mfma_f32_32x32x16_f16(aq0, cbF[0], sa, 0, 0, 0);
        sb = __builtin_amdgcn_mfma_f32_32x32x16_f16(aq1, cbF[1], sb, 0, 0, 0);
        sa = __builtin_amdgcn_mfma_f32_32x32x16_f16(aq2, cbF[2], sa, 0, 0, 0);
        sb = __builtin_amdgcn_mfma_f32_32x32x16_f16(aq3, cbF[3], sb, 0, 0, 0);
        sa = __builtin_amdgcn_mfma_f32_32x32x16_f16(aq4, cbF[4], sa, 0, 0, 0);
        sb = __builtin_amdgcn_mfma_f32_32x32x16_f16(aq5, cbF[5], sb, 0, 0, 0);
        sa = __builtin_amdgcn_mfma_f32_32x32x16_f16(aq6, cbF[6], sa, 0, 0, 0);

        float sc[16];
        sc[0]  = sa[0]  + sb[0]  + tv0[0];
        sc[1]  = sa[1]  + sb[1]  + tv0[1];
        sc[2]  = sa[2]  + sb[2]  + tv0[2];
        sc[3]  = sa[3]  + sb[3]  + tv0[3];
        sc[4]  = sa[4]  + sb[4]  + tv1[0];
        sc[5]  = sa[5]  + sb[5]  + tv1[1];
        sc[6]  = sa[6]  + sb[6]  + tv1[2];
        sc[7]  = sa[7]  + sb[7]  + tv1[3];
        sc[8]  = sa[8]  + sb[8]  + tv2[0];
        sc[9]  = sa[9]  + sb[9]  + tv2[1];
        sc[10] = sa[10] + sb[10] + tv2[2];
        sc[11] = sa[11] + sb[11] + tv2[3];
        sc[12] = sa[12] + sb[12] + tv3[0];
        sc[13] = sa[13] + sb[13] + tv3[1];
        sc[14] = sa[14] + sb[14] + tv3[2];
        sc[15] = sa[15] + sb[15] + tv3[3];

        // ---- tile max (tree) + defer-max rescale ----
        float t0 = fmaxf(sc[0], sc[1]),  t1 = fmaxf(sc[2], sc[3]);
        float t2 = fmaxf(sc[4], sc[5]),  t3 = fmaxf(sc[6], sc[7]);
        float t4 = fmaxf(sc[8], sc[9]),  t5 = fmaxf(sc[10], sc[11]);
        float t6 = fmaxf(sc[12], sc[13]), t7 = fmaxf(sc[14], sc[15]);
        t0 = fmaxf(t0, t1); t2 = fmaxf(t2, t3); t4 = fmaxf(t4, t5); t6 = fmaxf(t6, t7);
        float tm = fmaxf(fmaxf(t0, t2), fmaxf(t4, t6));
        tm = fmaxf(tm, __shfl_xor(tm, 32, 64));
        mtrue = fmaxf(mtrue, tm);

        if (__any(tm > m + THR)) {
            float mn = fmaxf(m, tm);
            float scale = __expf(m - mn);
            U0 *= scale; U1 *= scale; U2 *= scale; U3 *= scale;
            l *= scale;
            m = mn;
        }

        float ps = 0.f;
        #pragma unroll
        for (int r = 0; r < 16; ++r) { sc[r] = __expf(sc[r] - m); ps += sc[r]; }
        l += ps;

        // ---- P -> PV B-operand ----
        unsigned int pk[8], pr[8];
        #pragma unroll
        for (int h2 = 0; h2 < 8; ++h2) {
            PkU u; u.h2[0] = (_Float16)sc[2 * h2]; u.h2[1] = (_Float16)sc[2 * h2 + 1];
            pk[h2] = u.u;
            pr[h2] = (unsigned int)__shfl_xor((int)pk[h2], 32, 64);
        }
        FragU f0, f1;
        f0.u[0] = hi ? pr[2] : pk[0];
        f0.u[1] = hi ? pr[3] : pk[1];
        f0.u[2] = hi ? pk[2] : pr[0];
        f0.u[3] = hi ? pk[3] : pr[1];
        f1.u[0] = hi ? pr[6] : pk[4];
        f1.u[1] = hi ? pr[7] : pk[5];
        f1.u[2] = hi ? pk[6] : pr[4];
        f1.u[3] = hi ? pk[7] : pr[5];

        // ---- PV ----
        U0 = __builtin_amdgcn_mfma_f32_32x32x16_f16(av0, f0.v, U0, 0, 0, 0);
        U1 = __builtin_amdgcn_mfma_f32_32x32x16_f16(av2, f0.v, U1, 0, 0, 0);
        U2 = __builtin_amdgcn_mfma_f32_32x32x16_f16(av4, f0.v, U2, 0, 0, 0);
        U3 = __builtin_amdgcn_mfma_f32_32x32x16_f16(av6, f0.v, U3, 0, 0, 0);
        U0 = __builtin_amdgcn_mfma_f32_32x32x16_f16(av1, f1.v, U0, 0, 0, 0);
        U1 = __builtin_amdgcn_mfma_f32_32x32x16_f16(av3, f1.v, U1, 0, 0, 0);
        U2 = __builtin_amdgcn_mfma_f32_32x32x16_f16(av5, f1.v, U2, 0, 0, 0);
        U3 = __builtin_amdgcn_mfma_f32_32x32x16_f16(av7, f1.v, U3, 0, 0, 0);
    }

    l += __shfl_xor(l, 32, 64);

    // ---- stash per-wave partials ----
    #pragma unroll
    for (int r = 0; r < 16; ++r) {
        int dl = (r & 3) + 8 * (r >> 2) + 4 * hi;
        smU[w][dl][c31]      = (_Float16)U0[r];
        smU[w][32 + dl][c31] = (_Float16)U1[r];
        smU[w][64 + dl][c31] = (_Float16)U2[r];
        if (96 + dl < DIM) smU[w][96 + dl][c31] = (_Float16)U3[r];
    }
    if (lane < 32) { smM[w][c31] = m; smL[w][c31] = l; smMt[w][c31] = mtrue; }
    __syncthreads();

    // ---- split-K combine + epilogue ----
    {
        int i32 = tid & 31;
        int seg = tid >> 5;                  // 0..7
        float M = -INFINITY;
        #pragma unroll
        for (int ww = 0; ww < 4; ++ww) M = fmaxf(M, smM[ww][i32]);
        float ew[4];
        float L = 0.f, Mt = -INFINITY;
        #pragma unroll
        for (int ww = 0; ww < 4; ++ww) {
            ew[ww] = __expf(smM[ww][i32] - M);
            L += smL[ww][i32] * ew[ww];
            Mt = fmaxf(Mt, smMt[ww][i32]);
        }
        int row = i0 + i32;
        if (seg == 0) mfull[row] = a[row] + Mt;
        float invL = 1.f / L;
        for (int d = seg; d < DIM; d += 8) {
            float u = 0.f;
            #pragma unroll
            for (int ww = 0; ww < 4; ++ww) u += (float)smU[ww][d][i32] * ew[ww];
            float ua = u * invL;
            float cv = ctx[(size_t)row * DIM + d];
            size_t base = (size_t)row * 400;
            G[base + d]       = cv;
            G[base + 100 + d] = ua;
            G[base + 200 + d] = ua * cv;
        }
    }
}

// ---------------- b-softmax + h ----------------
__global__ void kernel_h(const float* __restrict__ mfull, const float* __restrict__ ctx,
                         float* __restrict__ hp) {
    __shared__ float sm[256];
    int t = threadIdx.x;
    float v = -INFINITY;
    for (int i = t; i < N_CTX; i += 256) v = fmaxf(v, mfull[i]);
    sm[t] = v; __syncthreads();
    for (int s = 128; s > 0; s >>= 1) { if (t < s) sm[t] = fmaxf(sm[t], sm[t + s]); __syncthreads(); }
    float M = sm[0];
    __syncthreads();
    float z = 0.f;
    for (int i = t; i < N_CTX; i += 256) z += __expf(mfull[i] - M);
    sm[t] = z; __syncthreads();
    for (int s = 128; s > 0; s >>= 1) { if (t < s) sm[t] += sm[t + s]; __syncthreads(); }
    float Z = sm[0];
    if (t < DIM) {
        int i0 = blockIdx.x * 64;
        float acc = 0.f;
        for (int r = 0; r < 64; ++r)
            acc += __expf(mfull[i0 + r] - M) * ctx[(size_t)(i0 + r) * DIM + t];
        hp[t * 256 + blockIdx.x] = acc / Z;
    }
}

__global__ void kernel_hred(const float* __restrict__ hp, float* __restrict__ h) {
    __shared__ float sm[4][128];
    int t = threadIdx.x;
    int d = t & 127, rep = t >> 7;
    float s = 0.f;
    if (d < DIM) for (int b = 0; b < 64; ++b) s += hp[d * 256 + rep * 64 + b];
    sm[rep][d] = s;
    __syncthreads();
    if (rep == 0 && d < DIM) h[d] = sm[0][d] + sm[1][d] + sm[2][d] + sm[3][d];
}

__global__ void kernel_g4(const float* __restrict__ ctx, const float* __restrict__ h,
                          float* __restrict__ G) {
    int idx = blockIdx.x * 256 + threadIdx.x;
    if (idx >= N_CTX * DIM) return;
    int i = idx / DIM;
    int d = idx - i * DIM;
    G[(size_t)i * 400 + 300 + d] = ctx[idx] * h[d];
}

// ---------------- launcher ----------------
extern "C" void kernel_launch(void* const* d_in, const int* in_sizes, int n_in,
                              void* d_out, int out_size, void* d_ws, size_t ws_size,
                              hipStream_t stream) {
    const float* ctx = (const float*)d_in[0];
    const float* q   = (const float*)d_in[1];
    const float* ker = (const float*)d_in[2];
    float* G = (float*)d_out;

    char* ws = (char*)d_ws;
    unsigned short* qb    = (unsigned short*)(ws);                 // 4096*128*2 = 1,048,576
    unsigned short* qT    = (unsigned short*)(ws + 1048576);       // 128*4096*2 = 1,048,576
    float*          t     = (float*)(ws + 2097152);                // 16,384
    float*          a     = (float*)(ws + 2113536);                // 65,536
    float*          mfull = (float*)(ws + 2179072);                // 65,536
    float*          hp    = (float*)(ws + 2244608);                // 102,400
    float*          h     = (float*)(ws + 2347008);                // 400

    prep_all<<<dim3(144), dim3(256), 0, stream>>>(q, ctx, ker, qb, qT, t, a);
    attn_main<<<dim3(512), dim3(256), 0, stream>>>(qb, qT, t, a, ctx, ker, G, mfull);
    kernel_h<<<dim3(256), dim3(256), 0, stream>>>(mfull, ctx, hp);
    kernel_hred<<<dim3(1), dim3(512), 0, stream>>>(hp, h);
    kernel_g4<<<dim3(6400), dim3(256), 0, stream>>>(ctx, h, G);
}